// Round 2
// baseline (102.465 us; speedup 1.0000x reference)
//
#include <hip/hip_runtime.h>
#include <math.h>

// Problem constants (S,N,B,T,D) = (8,8,2,2048,1024)
#define TPB 256

template <int CTRL>
__device__ __forceinline__ float dpp_add(float x) {
    int yi = __builtin_amdgcn_update_dpp(0, __float_as_int(x), CTRL, 0xF, 0xF, true);
    return x + __int_as_float(yi);
}

// Full 64-lane all-reduce sum: 4 DPP butterfly steps (VALU pipe) + 2 shuffle steps.
__device__ __forceinline__ float wave_sum(float x) {
    x = dpp_add<0xB1>(x);   // quad_perm [1,0,3,2]  = xor 1
    x = dpp_add<0x4E>(x);   // quad_perm [2,3,0,1]  = xor 2
    x = dpp_add<0x141>(x);  // row_half_mirror      = xor 7 -> oct sums
    x = dpp_add<0x140>(x);  // row_mirror           = xor 15 -> row(16) sums
    x += __shfl_xor(x, 16, 64);
    x += __shfl_xor(x, 32, 64);
    return x;
}

__global__ __launch_bounds__(TPB) void two_phase_attn_kernel(
    const float* __restrict__ q,    // [8][1024]
    const float* __restrict__ V,    // block_reps  [8][2][2048][1024]
    const float* __restrict__ P,    // partial_sums[8][2][2048][1024]
    const float* __restrict__ wgt,  // [1024]
    float* __restrict__ out)        // merged_out | merged_max | merged_lse
{
    constexpr int   N   = 8;
    constexpr int   D   = 1024;
    constexpr int   BT  = 4096;                 // B*T
    constexpr size_t ROW = (size_t)BT * D;      // stride per s (or n): 4194304
    constexpr size_t OUT_MM  = (size_t)8 * ROW; // 33554432
    constexpr size_t OUT_LSE = OUT_MM + BT * 8; // + 32768
    constexpr float SCALE = 0.03125f;           // 1/sqrt(1024)
    constexpr float EPS   = 1e-6f;

    __shared__ float sV[N][D];     // 32 KB
    __shared__ float sSsq[N];

    const int bt   = blockIdx.x;
    const int tid  = threadIdx.x;
    const int w    = tid >> 6;
    const int lane = tid & 63;
    const int s0 = 2 * w, s1 = s0 + 1;          // wave owns s-pair == n-pair
    const size_t btD = (size_t)bt * D;

    // ---- Stage V rows n0=s0, n1=s1 into LDS; accumulate sum-of-squares ----
    float ssqA = 0.f, ssqB = 0.f;
    #pragma unroll
    for (int j = 0; j < 4; ++j) {
        const int d = j * 256 + lane * 4;
        const float4 va = *(const float4*)(V + (size_t)s0 * ROW + btD + d);
        const float4 vb = *(const float4*)(V + (size_t)s1 * ROW + btD + d);
        *(float4*)(&sV[s0][d]) = va;
        *(float4*)(&sV[s1][d]) = vb;
        ssqA += va.x*va.x + va.y*va.y + va.z*va.z + va.w*va.w;
        ssqB += vb.x*vb.x + vb.y*vb.y + vb.z*vb.z + vb.w*vb.w;
    }

    // ---- q * norm_weight for this wave's two s rows (L2-resident) ----
    float4 qw0[4], qw1[4];
    #pragma unroll
    for (int j = 0; j < 4; ++j) {
        const int d = j * 256 + lane * 4;
        const float4 wv = *(const float4*)(wgt + d);
        const float4 a  = *(const float4*)(q + s0 * D + d);
        const float4 b  = *(const float4*)(q + s1 * D + d);
        qw0[j] = make_float4(a.x*wv.x, a.y*wv.y, a.z*wv.z, a.w*wv.w);
        qw1[j] = make_float4(b.x*wv.x, b.y*wv.y, b.z*wv.z, b.w*wv.w);
    }

    ssqA = wave_sum(ssqA);
    ssqB = wave_sum(ssqB);
    if (lane == 0) { sSsq[s0] = ssqA; sSsq[s1] = ssqB; }
    __syncthreads();

    // ---- Phase 2 global loads issued early (overlap with LDS dot phase) ----
    float4 p0[4], p1[4];
    #pragma unroll
    for (int j = 0; j < 4; ++j) {
        const int d = j * 256 + lane * 4;
        p0[j] = *(const float4*)(P + (size_t)s0 * ROW + btD + d);
        p1[j] = *(const float4*)(P + (size_t)s1 * ROW + btD + d);
    }

    // ---- Phase 1 dots: logits[s',n] raw dot(q*w, V[n]) ----
    float rinv[N];
    #pragma unroll
    for (int n = 0; n < N; ++n)
        rinv[n] = rsqrtf(sSsq[n] * (1.0f / 1024.0f) + EPS);

    float dot0[N], dot1[N];
    #pragma unroll
    for (int n = 0; n < N; ++n) { dot0[n] = 0.f; dot1[n] = 0.f; }
    #pragma unroll
    for (int n = 0; n < N; ++n) {
        #pragma unroll
        for (int j = 0; j < 4; ++j) {
            const int d = j * 256 + lane * 4;
            const float4 v = *(const float4*)(&sV[n][d]);
            dot0[n] += qw0[j].x*v.x + qw0[j].y*v.y + qw0[j].z*v.z + qw0[j].w*v.w;
            dot1[n] += qw1[j].x*v.x + qw1[j].y*v.y + qw1[j].z*v.z + qw1[j].w*v.w;
        }
    }
    #pragma unroll
    for (int n = 0; n < N; ++n) { dot0[n] = wave_sum(dot0[n]); dot1[n] = wave_sum(dot1[n]); }

    // ---- Phase 1 softmax over n (broadcast values, all lanes identical) ----
    float l0[N], l1[N];
    float m0 = -1e30f, m1 = -1e30f;
    #pragma unroll
    for (int n = 0; n < N; ++n) {
        l0[n] = dot0[n] * rinv[n] * SCALE;  m0 = fmaxf(m0, l0[n]);
        l1[n] = dot1[n] * rinv[n] * SCALE;  m1 = fmaxf(m1, l1[n]);
    }
    float e0[N], e1[N];
    float es0 = 0.f, es1 = 0.f;
    #pragma unroll
    for (int n = 0; n < N; ++n) {
        e0[n] = __expf(l0[n] - m0);  es0 += e0[n];
        e1[n] = __expf(l1[n] - m1);  es1 += e1[n];
    }

    // ---- Phase 2: rmsnorm(P) dot + merge scalars ----
    float ssq20 = 0.f, ssq21 = 0.f, dp0 = 0.f, dp1 = 0.f;
    #pragma unroll
    for (int j = 0; j < 4; ++j) {
        ssq20 += p0[j].x*p0[j].x + p0[j].y*p0[j].y + p0[j].z*p0[j].z + p0[j].w*p0[j].w;
        ssq21 += p1[j].x*p1[j].x + p1[j].y*p1[j].y + p1[j].z*p1[j].z + p1[j].w*p1[j].w;
        dp0   += qw0[j].x*p0[j].x + qw0[j].y*p0[j].y + qw0[j].z*p0[j].z + qw0[j].w*p0[j].w;
        dp1   += qw1[j].x*p1[j].x + qw1[j].y*p1[j].y + qw1[j].z*p1[j].z + qw1[j].w*p1[j].w;
    }
    ssq20 = wave_sum(ssq20);  ssq21 = wave_sum(ssq21);
    dp0   = wave_sum(dp0);    dp1   = wave_sum(dp1);

    const float im0 = dp0 * rsqrtf(ssq20 * (1.0f/1024.0f) + EPS) * SCALE;
    const float im1 = dp1 * rsqrtf(ssq21 * (1.0f/1024.0f) + EPS) * SCALE;

    const float mm0 = fmaxf(m0, im0),            mm1 = fmaxf(m1, im1);
    const float wi0 = __expf(m0 - mm0),          wi1 = __expf(m1 - mm1);
    const float wa0 = __expf(im0 - mm0),         wa1 = __expf(im1 - mm1);
    const float lse0 = __logf(wi0 * es0 + wa0) + mm0;   // exp(inter_lse-inter_max)==es
    const float lse1 = __logf(wi1 * es1 + wa1) + mm1;
    const float nrm0 = wi0 + wa0,                nrm1 = wi1 + wa1;
    const float cA0 = wi0 / (es0 * nrm0),        cA1 = wi1 / (es1 * nrm1);
    const float cp0 = wa0 / nrm0,                cp1 = wa1 / nrm1;

    // ---- Phase E: inter_out from LDS, merge, store ----
    float4 acc0[4], acc1[4];
    #pragma unroll
    for (int j = 0; j < 4; ++j) {
        acc0[j] = make_float4(0.f, 0.f, 0.f, 0.f);
        acc1[j] = make_float4(0.f, 0.f, 0.f, 0.f);
    }
    #pragma unroll
    for (int n = 0; n < N; ++n) {
        const float c0 = e0[n], c1 = e1[n];
        #pragma unroll
        for (int j = 0; j < 4; ++j) {
            const int d = j * 256 + lane * 4;
            const float4 v = *(const float4*)(&sV[n][d]);
            acc0[j].x += c0 * v.x; acc0[j].y += c0 * v.y; acc0[j].z += c0 * v.z; acc0[j].w += c0 * v.w;
            acc1[j].x += c1 * v.x; acc1[j].y += c1 * v.y; acc1[j].z += c1 * v.z; acc1[j].w += c1 * v.w;
        }
    }
    #pragma unroll
    for (int j = 0; j < 4; ++j) {
        const int d = j * 256 + lane * 4;
        float4 o0, o1;
        o0.x = cA0 * acc0[j].x + cp0 * p0[j].x;
        o0.y = cA0 * acc0[j].y + cp0 * p0[j].y;
        o0.z = cA0 * acc0[j].z + cp0 * p0[j].z;
        o0.w = cA0 * acc0[j].w + cp0 * p0[j].w;
        o1.x = cA1 * acc1[j].x + cp1 * p1[j].x;
        o1.y = cA1 * acc1[j].y + cp1 * p1[j].y;
        o1.z = cA1 * acc1[j].z + cp1 * p1[j].z;
        o1.w = cA1 * acc1[j].w + cp1 * p1[j].w;
        *(float4*)(out + (size_t)s0 * ROW + btD + d) = o0;
        *(float4*)(out + (size_t)s1 * ROW + btD + d) = o1;
    }
    if (lane == 0) {
        out[OUT_MM  + (size_t)s0 * BT + bt] = mm0;
        out[OUT_MM  + (size_t)s1 * BT + bt] = mm1;
        out[OUT_LSE + (size_t)s0 * BT + bt] = lse0;
        out[OUT_LSE + (size_t)s1 * BT + bt] = lse1;
    }
}

extern "C" void kernel_launch(void* const* d_in, const int* in_sizes, int n_in,
                              void* d_out, int out_size, void* d_ws, size_t ws_size,
                              hipStream_t stream) {
    const float* q   = (const float*)d_in[0];   // pseudo_queries [8,1024]
    const float* V   = (const float*)d_in[1];   // block_reps     [8,2,2048,1024]
    const float* P   = (const float*)d_in[2];   // partial_sums   [8,2,2048,1024]
    const float* wgt = (const float*)d_in[3];   // norm_weight    [1024]
    float* o = (float*)d_out;

    two_phase_attn_kernel<<<4096, TPB, 0, stream>>>(q, V, P, wgt, o);
}